// Round 1
// baseline (2471.964 us; speedup 1.0000x reference)
//
#include <hip/hip_runtime.h>
#include <cmath>

#define NCC 151
#define NRCH 51
#define BDIM 32
#define NOBJ 100
#define DDIM 4096
#define HDIM 1024
#define TDIM (BDIM * NOBJ)   // 3200

// ---------------------------------------------------------------------------
// fp32 tiled GEMM: C[M,N] = act(A[M,K] @ B[K,N]) (+ addsrc)
// BM=BN=64, BK=16, 256 threads, 4x4 micro-tile per thread.
// All dims here are multiples of the tile sizes (M=3200, N/K in {1024,4096}),
// so no bounds checks.
// ---------------------------------------------------------------------------
template <bool RELU, bool ADD>
__global__ __launch_bounds__(256) void gemm_kernel(
    const float* __restrict__ A, const float* __restrict__ B,
    const float* __restrict__ addsrc, float* __restrict__ C,
    int M, int N, int K) {
  __shared__ float As[16][65];  // [k][m]
  __shared__ float Bs[16][65];  // [k][n]
  const int tid = threadIdx.x;
  const int bm = blockIdx.y * 64;
  const int bn = blockIdx.x * 64;
  const int tr = (tid >> 4) * 4;  // row offset in tile
  const int tc = (tid & 15) * 4;  // col offset in tile

  float acc[4][4] = {};

  for (int k0 = 0; k0 < K; k0 += 16) {
#pragma unroll
    for (int i = 0; i < 4; ++i) {
      int e = tid + i * 256;  // 0..1023
      int m = e >> 4, kk = e & 15;
      As[kk][m] = A[(size_t)(bm + m) * K + (k0 + kk)];
      int kk2 = e >> 6, n = e & 63;
      Bs[kk2][n] = B[(size_t)(k0 + kk2) * N + (bn + n)];
    }
    __syncthreads();
#pragma unroll
    for (int kk = 0; kk < 16; ++kk) {
      float a[4], b[4];
#pragma unroll
      for (int u = 0; u < 4; ++u) a[u] = As[kk][tr + u];
#pragma unroll
      for (int v = 0; v < 4; ++v) b[v] = Bs[kk][tc + v];
#pragma unroll
      for (int u = 0; u < 4; ++u)
#pragma unroll
        for (int v = 0; v < 4; ++v) acc[u][v] += a[u] * b[v];
    }
    __syncthreads();
  }

#pragma unroll
  for (int u = 0; u < 4; ++u) {
#pragma unroll
    for (int v = 0; v < 4; ++v) {
      float val = acc[u][v];
      if (RELU) val = fmaxf(val, 0.0f);
      size_t off = (size_t)(bm + tr + u) * N + (bn + tc + v);
      if (ADD) val += addsrc[off];
      C[off] = val;
    }
  }
}

// ---------------------------------------------------------------------------
// Build x0[b][c][i][j] = freq_emb[(preds[b,i]*NCC + preds[b,j])][c]
// ---------------------------------------------------------------------------
__global__ __launch_bounds__(256) void build_x_kernel(
    const float* __restrict__ femb, const int* __restrict__ preds,
    float* __restrict__ x0) {
  size_t idx = (size_t)blockIdx.x * 256 + threadIdx.x;
  const size_t total = (size_t)BDIM * NRCH * NOBJ * NOBJ;
  if (idx >= total) return;
  int j = idx % NOBJ;
  int i = (idx / NOBJ) % NOBJ;
  int c = (idx / (NOBJ * NOBJ)) % NRCH;
  int b = idx / ((size_t)NRCH * NOBJ * NOBJ);
  int li = preds[b * NOBJ + i];
  int lj = preds[b * NOBJ + j];
  x0[idx] = femb[(size_t)(li * NCC + lj) * NRCH + c];
}

// ---------------------------------------------------------------------------
// conv1: (B,51,100,100) -> (B,10,100,100), 3x3 SAME, weights (10,51,3,3)
// ---------------------------------------------------------------------------
__global__ __launch_bounds__(256) void conv1_kernel(
    const float* __restrict__ x, const float* __restrict__ w,
    float* __restrict__ y) {
  __shared__ float ws[10 * NRCH * 9];
  for (int i = threadIdx.x; i < 10 * NRCH * 9; i += 256) ws[i] = w[i];
  __syncthreads();
  size_t idx = (size_t)blockIdx.x * 256 + threadIdx.x;
  const size_t total = (size_t)BDIM * 10 * NOBJ * NOBJ;
  if (idx >= total) return;
  int j = idx % NOBJ;
  int i = (idx / NOBJ) % NOBJ;
  int co = (idx / (NOBJ * NOBJ)) % 10;
  int b = idx / (10 * NOBJ * NOBJ);
  const float* xb = x + (size_t)b * NRCH * NOBJ * NOBJ;
  const float* wc = ws + co * NRCH * 9;
  float acc = 0.0f;
  for (int ci = 0; ci < NRCH; ++ci) {
    const float* xc = xb + (size_t)ci * NOBJ * NOBJ;
    const float* wk = wc + ci * 9;
#pragma unroll
    for (int kh = 0; kh < 3; ++kh) {
      int ii = i + kh - 1;
      if (ii < 0 || ii >= NOBJ) continue;
#pragma unroll
      for (int kw = 0; kw < 3; ++kw) {
        int jj = j + kw - 1;
        if (jj < 0 || jj >= NOBJ) continue;
        acc += wk[kh * 3 + kw] * xc[ii * NOBJ + jj];
      }
    }
  }
  y[idx] = acc;
}

// ---------------------------------------------------------------------------
// conv2: (B,10,100,100) -> (B,5,100,100), 3x3 SAME, weights (5,10,3,3)
// ---------------------------------------------------------------------------
__global__ __launch_bounds__(256) void conv2_kernel(
    const float* __restrict__ x, const float* __restrict__ w,
    float* __restrict__ y) {
  __shared__ float ws[5 * 10 * 9];
  for (int i = threadIdx.x; i < 5 * 10 * 9; i += 256) ws[i] = w[i];
  __syncthreads();
  size_t idx = (size_t)blockIdx.x * 256 + threadIdx.x;
  const size_t total = (size_t)BDIM * 5 * NOBJ * NOBJ;
  if (idx >= total) return;
  int j = idx % NOBJ;
  int i = (idx / NOBJ) % NOBJ;
  int co = (idx / (NOBJ * NOBJ)) % 5;
  int b = idx / (5 * NOBJ * NOBJ);
  const float* xb = x + (size_t)b * 10 * NOBJ * NOBJ;
  const float* wc = ws + co * 10 * 9;
  float acc = 0.0f;
  for (int ci = 0; ci < 10; ++ci) {
    const float* xc = xb + (size_t)ci * NOBJ * NOBJ;
    const float* wk = wc + ci * 9;
#pragma unroll
    for (int kh = 0; kh < 3; ++kh) {
      int ii = i + kh - 1;
      if (ii < 0 || ii >= NOBJ) continue;
#pragma unroll
      for (int kw = 0; kw < 3; ++kw) {
        int jj = j + kw - 1;
        if (jj < 0 || jj >= NOBJ) continue;
        acc += wk[kh * 3 + kw] * xc[ii * NOBJ + jj];
      }
    }
  }
  y[idx] = acc;
}

// ---------------------------------------------------------------------------
// conv3 + tanh: (B,5,100,100) -> adj (B,100,100), 1x1, weights (1,5,1,1)
// ---------------------------------------------------------------------------
__global__ __launch_bounds__(256) void conv3_kernel(
    const float* __restrict__ x, const float* __restrict__ w,
    float* __restrict__ adj) {
  size_t idx = (size_t)blockIdx.x * 256 + threadIdx.x;
  const size_t total = (size_t)BDIM * NOBJ * NOBJ;
  if (idx >= total) return;
  int pix = idx % (NOBJ * NOBJ);
  int b = idx / (NOBJ * NOBJ);
  const float* xb = x + (size_t)b * 5 * NOBJ * NOBJ;
  float acc = 0.0f;
#pragma unroll
  for (int c = 0; c < 5; ++c) acc += w[c] * xb[(size_t)c * NOBJ * NOBJ + pix];
  adj[idx] = tanhf(acc);
}

// ---------------------------------------------------------------------------
// einsum: ofl_u[b,n,h] = sum_m adj[b,n,m] * obj_u1[b,m,h]
// one block per (b,n); 256 threads cover H=1024 (4 per thread)
// ---------------------------------------------------------------------------
__global__ __launch_bounds__(256) void einsum_kernel(
    const float* __restrict__ adj, const float* __restrict__ u1,
    float* __restrict__ out) {
  int b = blockIdx.x / NOBJ;
  int n = blockIdx.x % NOBJ;
  __shared__ float arow[NOBJ];
  if (threadIdx.x < NOBJ)
    arow[threadIdx.x] = adj[((size_t)b * NOBJ + n) * NOBJ + threadIdx.x];
  __syncthreads();
  const float* ub = u1 + (size_t)b * NOBJ * HDIM;
#pragma unroll
  for (int rep = 0; rep < 4; ++rep) {
    int h = threadIdx.x + rep * 256;
    float acc = 0.0f;
    for (int m = 0; m < NOBJ; ++m) acc += arow[m] * ub[(size_t)m * HDIM + h];
    out[((size_t)b * NOBJ + n) * HDIM + h] = acc;
  }
}

// ---------------------------------------------------------------------------
extern "C" void kernel_launch(void* const* d_in, const int* in_sizes, int n_in,
                              void* d_out, int out_size, void* d_ws,
                              size_t ws_size, hipStream_t stream) {
  const float* enc = (const float*)d_in[0];
  const float* W_comp = (const float*)d_in[1];
  const float* W_ou1 = (const float*)d_in[2];
  const float* W_ofc = (const float*)d_in[3];
  const float* W_dec = (const float*)d_in[4];
  const float* conv1w = (const float*)d_in[5];
  const float* conv2w = (const float*)d_in[6];
  const float* conv3w = (const float*)d_in[7];
  const float* femb = (const float*)d_in[8];
  const int* preds = (const int*)d_in[9];
  float* out = (float*)d_out;
  float* ws = (float*)d_ws;

  // workspace layout (floats)
  float* obj_u1 = ws;                       // 3,276,800
  float* comp = ws + 3276800;               // 3,276,800 (dead after obj_u1)
  float* x0 = ws + 6553600;                 // 16,320,000 (dead after conv1)
  float* x1 = ws + 22873600;                // 3,200,000
  float* x2 = ws + 26073600;                // 1,600,000
  float* adj = ws + 27673600;               // 320,000
  float* ofl_u = comp;                      // reuse
  float* u_m = x0;                          // reuse

  // 1. comp = relu(enc @ W_comp)            (3200x4096)@(4096x1024)
  gemm_kernel<true, false><<<dim3(HDIM / 64, TDIM / 64), 256, 0, stream>>>(
      enc, W_comp, nullptr, comp, TDIM, HDIM, DDIM);
  // 2. obj_u1 = relu(comp @ W_ou1)          (3200x1024)@(1024x1024)
  gemm_kernel<true, false><<<dim3(HDIM / 64, TDIM / 64), 256, 0, stream>>>(
      comp, W_ou1, nullptr, obj_u1, TDIM, HDIM, HDIM);
  // 3. x0 gather
  {
    size_t total = (size_t)BDIM * NRCH * NOBJ * NOBJ;
    build_x_kernel<<<(total + 255) / 256, 256, 0, stream>>>(femb, preds, x0);
  }
  // 4. conv1
  {
    size_t total = (size_t)BDIM * 10 * NOBJ * NOBJ;
    conv1_kernel<<<(total + 255) / 256, 256, 0, stream>>>(x0, conv1w, x1);
  }
  // 5. conv2
  {
    size_t total = (size_t)BDIM * 5 * NOBJ * NOBJ;
    conv2_kernel<<<(total + 255) / 256, 256, 0, stream>>>(x1, conv2w, x2);
  }
  // 6. conv3 + tanh
  {
    size_t total = (size_t)BDIM * NOBJ * NOBJ;
    conv3_kernel<<<(total + 255) / 256, 256, 0, stream>>>(x2, conv3w, adj);
  }
  // 7. einsum
  einsum_kernel<<<BDIM * NOBJ, 256, 0, stream>>>(adj, obj_u1, ofl_u);
  // 8. u_m = relu(ofl_u @ W_ofc)            (3200x1024)@(1024x1024)
  gemm_kernel<true, false><<<dim3(HDIM / 64, TDIM / 64), 256, 0, stream>>>(
      ofl_u, W_ofc, nullptr, u_m, TDIM, HDIM, HDIM);
  // 9. out = relu(u_m @ W_dec) + enc        (3200x1024)@(1024x4096)
  gemm_kernel<true, true><<<dim3(DDIM / 64, TDIM / 64), 256, 0, stream>>>(
      u_m, W_dec, enc, out, TDIM, DDIM, HDIM);
}

// Round 2
// 1007.276 us; speedup vs baseline: 2.4541x; 2.4541x over previous
//
#include <hip/hip_runtime.h>
#include <cmath>

#define NCC 151
#define NRCH 51
#define BDIM 32
#define NOBJ 100
#define DDIM 4096
#define HDIM 1024
#define TDIM (BDIM * NOBJ)   // 3200

typedef __bf16 bf16_t;
typedef __bf16 bf16x8 __attribute__((ext_vector_type(8)));
typedef __bf16 bf16x4 __attribute__((ext_vector_type(4)));
typedef float f32x4 __attribute__((ext_vector_type(4)));

// ---------------------------------------------------------------------------
// bf16 MFMA GEMM (m97 structure): C[M,N] = act(A[M,K] @ Bt[N,K]^T) (+ add)
// 128x128 tile, BK=64, 256 threads = 4 waves (2x2), 16x16x32 MFMA.
// LDS tiles [128 rows][64 k] bf16, row stride 128B, XOR-swizzled:
//   element (row,k) lives at byte row*128 + (((k/8) ^ (row&7))<<4) + (k%8)*2
// Staged via global_load_lds(16B): linear LDS dest + inverse-swizzled global
// source (guide rule #21). ds_read_b128 fragment reads then land conflict-free
// (8 distinct 16B units per 8 rows; 2-way aliasing is free per m136).
// ---------------------------------------------------------------------------
template <bool RELU, bool ADDF32OUT>
__global__ __launch_bounds__(256) void gemm_bf16(
    const bf16_t* __restrict__ A,   // [M][K] row-major
    const bf16_t* __restrict__ Bt,  // [N][K] row-major (pre-transposed weight)
    const float* __restrict__ add,  // fp32 residual when ADDF32OUT
    void* __restrict__ Cout,        // bf16 [M][N], or fp32 when ADDF32OUT
    int N, int K) {
  __shared__ __align__(16) bf16_t Asm[128 * 64];
  __shared__ __align__(16) bf16_t Bsm[128 * 64];
  const int tid = threadIdx.x;
  const int lane = tid & 63;
  const int w = tid >> 6;           // wave 0..3
  const int wm = w >> 1, wn = w & 1;
  const int bm = blockIdx.y * 128, bn = blockIdx.x * 128;
  const int lr = lane & 15;         // fragment row
  const int lk = lane >> 4;         // k sub-slot (0..3)

  f32x4 acc[4][4];
#pragma unroll
  for (int m = 0; m < 4; ++m)
#pragma unroll
    for (int n = 0; n < 4; ++n) acc[m][n] = (f32x4){0.f, 0.f, 0.f, 0.f};

  const int srow = tid >> 3;   // staging row within 32-row group
  const int sslot = tid & 7;   // staging 16B slot within row

  char* ldsA = (char*)Asm;
  char* ldsB = (char*)Bsm;

  for (int kt = 0; kt < K; kt += 64) {
    __syncthreads();  // previous tile's reads complete before overwrite
#pragma unroll
    for (int i = 0; i < 4; ++i) {
      const int row = i * 32 + srow;
      const int kc = sslot ^ (row & 7);  // inverse-swizzled global k-chunk
      const bf16_t* ga = A + (size_t)(bm + row) * K + kt + kc * 8;
      const bf16_t* gb = Bt + (size_t)(bn + row) * K + kt + kc * 8;
      __builtin_amdgcn_global_load_lds(
          (const __attribute__((address_space(1))) void*)ga,
          (__attribute__((address_space(3))) void*)(ldsA + i * 4096 + w * 1024),
          16, 0, 0);
      __builtin_amdgcn_global_load_lds(
          (const __attribute__((address_space(1))) void*)gb,
          (__attribute__((address_space(3))) void*)(ldsB + i * 4096 + w * 1024),
          16, 0, 0);
    }
    __syncthreads();  // compiler drains vmcnt before barrier

    bf16x8 af[4][2], bfr[4][2];
#pragma unroll
    for (int m = 0; m < 4; ++m) {
      const int row = wm * 64 + m * 16 + lr;
#pragma unroll
      for (int kk = 0; kk < 2; ++kk) {
        const int slot = kk * 4 + lk;
        af[m][kk] =
            *(const bf16x8*)(ldsA + row * 128 + ((slot ^ (lr & 7)) << 4));
      }
    }
#pragma unroll
    for (int n = 0; n < 4; ++n) {
      const int row = wn * 64 + n * 16 + lr;
#pragma unroll
      for (int kk = 0; kk < 2; ++kk) {
        const int slot = kk * 4 + lk;
        bfr[n][kk] =
            *(const bf16x8*)(ldsB + row * 128 + ((slot ^ (lr & 7)) << 4));
      }
    }
#pragma unroll
    for (int m = 0; m < 4; ++m)
#pragma unroll
      for (int n = 0; n < 4; ++n) {
        acc[m][n] = __builtin_amdgcn_mfma_f32_16x16x32_bf16(
            af[m][0], bfr[n][0], acc[m][n], 0, 0, 0);
        acc[m][n] = __builtin_amdgcn_mfma_f32_16x16x32_bf16(
            af[m][1], bfr[n][1], acc[m][n], 0, 0, 0);
      }
  }

  // epilogue: C/D layout col=lane&15, row=(lane>>4)*4+reg  [m89-verified]
  const int or0 = bm + wm * 64 + lk * 4;
  const int oc0 = bn + wn * 64 + lr;
#pragma unroll
  for (int m = 0; m < 4; ++m)
#pragma unroll
    for (int n = 0; n < 4; ++n)
#pragma unroll
      for (int r = 0; r < 4; ++r) {
        float v = acc[m][n][r];
        if (RELU) v = fmaxf(v, 0.f);
        const size_t off = (size_t)(or0 + m * 16 + r) * N + (oc0 + n * 16);
        if (ADDF32OUT)
          ((float*)Cout)[off] = v + add[off];
        else
          ((bf16_t*)Cout)[off] = (bf16_t)v;
      }
}

// ---------------------------------------------------------------------------
// fp32 -> bf16 (vectorized float4 -> bf16x4)
// ---------------------------------------------------------------------------
__global__ __launch_bounds__(256) void cvt_bf16_kernel(
    const float* __restrict__ in, bf16_t* __restrict__ out, int n4) {
  int i = blockIdx.x * 256 + threadIdx.x;
  if (i >= n4) return;
  float4 v = ((const float4*)in)[i];
  bf16x4 o = {(bf16_t)v.x, (bf16_t)v.y, (bf16_t)v.z, (bf16_t)v.w};
  ((bf16x4*)out)[i] = o;
}

// ---------------------------------------------------------------------------
// W[K][N] fp32 -> Wt[N][K] bf16, 32x32 LDS tile transpose
// ---------------------------------------------------------------------------
__global__ __launch_bounds__(256) void transT_kernel(
    const float* __restrict__ in, bf16_t* __restrict__ out, int K, int N) {
  __shared__ float t[32][33];
  const int n0 = blockIdx.x * 32, k0 = blockIdx.y * 32;
  const int tx = threadIdx.x & 31, ty = threadIdx.x >> 5;  // 32 x 8
#pragma unroll
  for (int i = 0; i < 4; ++i)
    t[ty + i * 8][tx] = in[(size_t)(k0 + ty + i * 8) * N + n0 + tx];
  __syncthreads();
#pragma unroll
  for (int i = 0; i < 4; ++i)
    out[(size_t)(n0 + ty + i * 8) * K + k0 + tx] = (bf16_t)t[tx][ty + i * 8];
}

// ---------------------------------------------------------------------------
// x0[b][c][i][j] = freq_emb[(preds[b,i]*NCC + preds[b,j])][c]   (fp32)
// ---------------------------------------------------------------------------
__global__ __launch_bounds__(256) void build_x_kernel(
    const float* __restrict__ femb, const int* __restrict__ preds,
    float* __restrict__ x0) {
  size_t idx = (size_t)blockIdx.x * 256 + threadIdx.x;
  const size_t total = (size_t)BDIM * NRCH * NOBJ * NOBJ;
  if (idx >= total) return;
  int j = idx % NOBJ;
  int i = (idx / NOBJ) % NOBJ;
  int c = (idx / (NOBJ * NOBJ)) % NRCH;
  int b = idx / ((size_t)NRCH * NOBJ * NOBJ);
  int li = preds[b * NOBJ + i];
  int lj = preds[b * NOBJ + j];
  x0[idx] = femb[(size_t)(li * NCC + lj) * NRCH + c];
}

// ---------------------------------------------------------------------------
// conv1: (B,51,100,100) -> (B,10,100,100), 3x3 SAME
// ---------------------------------------------------------------------------
__global__ __launch_bounds__(256) void conv1_kernel(
    const float* __restrict__ x, const float* __restrict__ w,
    float* __restrict__ y) {
  __shared__ float ws[10 * NRCH * 9];
  for (int i = threadIdx.x; i < 10 * NRCH * 9; i += 256) ws[i] = w[i];
  __syncthreads();
  size_t idx = (size_t)blockIdx.x * 256 + threadIdx.x;
  const size_t total = (size_t)BDIM * 10 * NOBJ * NOBJ;
  if (idx >= total) return;
  int j = idx % NOBJ;
  int i = (idx / NOBJ) % NOBJ;
  int co = (idx / (NOBJ * NOBJ)) % 10;
  int b = idx / (10 * NOBJ * NOBJ);
  const float* xb = x + (size_t)b * NRCH * NOBJ * NOBJ;
  const float* wc = ws + co * NRCH * 9;
  float acc = 0.0f;
  for (int ci = 0; ci < NRCH; ++ci) {
    const float* xc = xb + (size_t)ci * NOBJ * NOBJ;
    const float* wk = wc + ci * 9;
#pragma unroll
    for (int kh = 0; kh < 3; ++kh) {
      int ii = i + kh - 1;
      if (ii < 0 || ii >= NOBJ) continue;
#pragma unroll
      for (int kw = 0; kw < 3; ++kw) {
        int jj = j + kw - 1;
        if (jj < 0 || jj >= NOBJ) continue;
        acc += wk[kh * 3 + kw] * xc[ii * NOBJ + jj];
      }
    }
  }
  y[idx] = acc;
}

// ---------------------------------------------------------------------------
// conv2: (B,10,100,100) -> (B,5,100,100), 3x3 SAME
// ---------------------------------------------------------------------------
__global__ __launch_bounds__(256) void conv2_kernel(
    const float* __restrict__ x, const float* __restrict__ w,
    float* __restrict__ y) {
  __shared__ float ws[5 * 10 * 9];
  for (int i = threadIdx.x; i < 5 * 10 * 9; i += 256) ws[i] = w[i];
  __syncthreads();
  size_t idx = (size_t)blockIdx.x * 256 + threadIdx.x;
  const size_t total = (size_t)BDIM * 5 * NOBJ * NOBJ;
  if (idx >= total) return;
  int j = idx % NOBJ;
  int i = (idx / NOBJ) % NOBJ;
  int co = (idx / (NOBJ * NOBJ)) % 5;
  int b = idx / (5 * NOBJ * NOBJ);
  const float* xb = x + (size_t)b * 10 * NOBJ * NOBJ;
  const float* wc = ws + co * 10 * 9;
  float acc = 0.0f;
  for (int ci = 0; ci < 10; ++ci) {
    const float* xc = xb + (size_t)ci * NOBJ * NOBJ;
    const float* wk = wc + ci * 9;
#pragma unroll
    for (int kh = 0; kh < 3; ++kh) {
      int ii = i + kh - 1;
      if (ii < 0 || ii >= NOBJ) continue;
#pragma unroll
      for (int kw = 0; kw < 3; ++kw) {
        int jj = j + kw - 1;
        if (jj < 0 || jj >= NOBJ) continue;
        acc += wk[kh * 3 + kw] * xc[ii * NOBJ + jj];
      }
    }
  }
  y[idx] = acc;
}

// ---------------------------------------------------------------------------
// conv3 + tanh: (B,5,100,100) -> adj (B,100,100), 1x1
// ---------------------------------------------------------------------------
__global__ __launch_bounds__(256) void conv3_kernel(
    const float* __restrict__ x, const float* __restrict__ w,
    float* __restrict__ adj) {
  size_t idx = (size_t)blockIdx.x * 256 + threadIdx.x;
  const size_t total = (size_t)BDIM * NOBJ * NOBJ;
  if (idx >= total) return;
  int pix = idx % (NOBJ * NOBJ);
  int b = idx / (NOBJ * NOBJ);
  const float* xb = x + (size_t)b * 5 * NOBJ * NOBJ;
  float acc = 0.0f;
#pragma unroll
  for (int c = 0; c < 5; ++c) acc += w[c] * xb[(size_t)c * NOBJ * NOBJ + pix];
  adj[idx] = tanhf(acc);
}

// ---------------------------------------------------------------------------
// einsum: ofl_u[b,n,h] = sum_m adj[b,n,m] * obj_u1[b,m,h]  (bf16 in/out)
// ---------------------------------------------------------------------------
__global__ __launch_bounds__(256) void einsum_kernel(
    const float* __restrict__ adj, const bf16_t* __restrict__ u1,
    bf16_t* __restrict__ out) {
  int b = blockIdx.x / NOBJ;
  int n = blockIdx.x % NOBJ;
  __shared__ float arow[NOBJ];
  if (threadIdx.x < NOBJ)
    arow[threadIdx.x] = adj[((size_t)b * NOBJ + n) * NOBJ + threadIdx.x];
  __syncthreads();
  const bf16_t* ub = u1 + (size_t)b * NOBJ * HDIM;
  const int h0 = threadIdx.x * 4;
  float a0 = 0.f, a1 = 0.f, a2 = 0.f, a3 = 0.f;
  for (int m = 0; m < NOBJ; ++m) {
    float a = arow[m];
    bf16x4 v = *(const bf16x4*)(ub + (size_t)m * HDIM + h0);
    a0 += a * (float)v[0];
    a1 += a * (float)v[1];
    a2 += a * (float)v[2];
    a3 += a * (float)v[3];
  }
  bf16x4 o = {(bf16_t)a0, (bf16_t)a1, (bf16_t)a2, (bf16_t)a3};
  *(bf16x4*)(out + ((size_t)b * NOBJ + n) * HDIM + h0) = o;
}

// ---------------------------------------------------------------------------
extern "C" void kernel_launch(void* const* d_in, const int* in_sizes, int n_in,
                              void* d_out, int out_size, void* d_ws,
                              size_t ws_size, hipStream_t stream) {
  const float* enc = (const float*)d_in[0];
  const float* W_comp = (const float*)d_in[1];
  const float* W_ou1 = (const float*)d_in[2];
  const float* W_ofc = (const float*)d_in[3];
  const float* W_dec = (const float*)d_in[4];
  const float* conv1w = (const float*)d_in[5];
  const float* conv2w = (const float*)d_in[6];
  const float* conv3w = (const float*)d_in[7];
  const float* femb = (const float*)d_in[8];
  const int* preds = (const int*)d_in[9];
  float* out = (float*)d_out;
  char* wsb = (char*)d_ws;

  // workspace layout (bytes); region0 [0, 65.28M) is time-shared:
  //   phase A: enc_bf16 / WcompT / Wou1T / comp   (dead before gather)
  //   phase B: x0                                  (dead after conv1)
  //   phase C: ofl_u / WofcT / u_m / WdecT
  bf16_t* encb   = (bf16_t*)(wsb + 0);          // 26,214,400
  bf16_t* WcompT = (bf16_t*)(wsb + 26214400);   //  8,388,608
  bf16_t* Wou1T  = (bf16_t*)(wsb + 34603008);   //  2,097,152
  bf16_t* comp   = (bf16_t*)(wsb + 36700160);   //  6,553,600 (ends 43.25M)
  float*  x0     = (float*)(wsb + 0);           // 65,280,000
  bf16_t* obj_u1 = (bf16_t*)(wsb + 65280000);   //  6,553,600
  float*  x1     = (float*)(wsb + 71833600);    // 12,800,000
  float*  x2     = (float*)(wsb + 84633600);    //  6,400,000
  float*  adj    = (float*)(wsb + 91033600);    //  1,280,000 (ends 92.3M)
  bf16_t* ofl_u  = (bf16_t*)(wsb + 0);          //  6,553,600
  bf16_t* WofcT  = (bf16_t*)(wsb + 6553600);    //  2,097,152
  bf16_t* u_m    = (bf16_t*)(wsb + 8650752);    //  6,553,600
  bf16_t* WdecT  = (bf16_t*)(wsb + 15204352);   //  8,388,608 (ends 23.6M)

  // --- conversions for GEMM1/2 ---
  cvt_bf16_kernel<<<(TDIM * DDIM / 4 + 255) / 256, 256, 0, stream>>>(
      enc, encb, TDIM * DDIM / 4);
  transT_kernel<<<dim3(HDIM / 32, DDIM / 32), 256, 0, stream>>>(
      W_comp, WcompT, DDIM, HDIM);
  transT_kernel<<<dim3(HDIM / 32, HDIM / 32), 256, 0, stream>>>(
      W_ou1, Wou1T, HDIM, HDIM);

  // 1. comp = relu(enc @ W_comp)   M=3200 N=1024 K=4096
  gemm_bf16<true, false><<<dim3(HDIM / 128, TDIM / 128), 256, 0, stream>>>(
      encb, WcompT, nullptr, comp, HDIM, DDIM);
  // 2. obj_u1 = relu(comp @ W_ou1) M=3200 N=1024 K=1024
  gemm_bf16<true, false><<<dim3(HDIM / 128, TDIM / 128), 256, 0, stream>>>(
      comp, Wou1T, nullptr, obj_u1, HDIM, HDIM);

  // 3. gather (overwrites region0 phase A)
  {
    size_t total = (size_t)BDIM * NRCH * NOBJ * NOBJ;
    build_x_kernel<<<(total + 255) / 256, 256, 0, stream>>>(femb, preds, x0);
  }
  // 4-6. convs
  {
    size_t total = (size_t)BDIM * 10 * NOBJ * NOBJ;
    conv1_kernel<<<(total + 255) / 256, 256, 0, stream>>>(x0, conv1w, x1);
  }
  {
    size_t total = (size_t)BDIM * 5 * NOBJ * NOBJ;
    conv2_kernel<<<(total + 255) / 256, 256, 0, stream>>>(x1, conv2w, x2);
  }
  {
    size_t total = (size_t)BDIM * NOBJ * NOBJ;
    conv3_kernel<<<(total + 255) / 256, 256, 0, stream>>>(x2, conv3w, adj);
  }

  // conversions for GEMM3/4 (region0 free after conv1)
  transT_kernel<<<dim3(HDIM / 32, HDIM / 32), 256, 0, stream>>>(
      W_ofc, WofcT, HDIM, HDIM);
  transT_kernel<<<dim3(DDIM / 32, HDIM / 32), 256, 0, stream>>>(
      W_dec, WdecT, HDIM, DDIM);

  // 7. einsum -> ofl_u (bf16)
  einsum_kernel<<<BDIM * NOBJ, 256, 0, stream>>>(adj, obj_u1, ofl_u);

  // 8. u_m = relu(ofl_u @ W_ofc)   M=3200 N=1024 K=1024
  gemm_bf16<true, false><<<dim3(HDIM / 128, TDIM / 128), 256, 0, stream>>>(
      ofl_u, WofcT, nullptr, u_m, HDIM, HDIM);
  // 9. out = relu(u_m @ W_dec) + enc   M=3200 N=4096 K=1024  (fp32 out)
  gemm_bf16<true, true><<<dim3(DDIM / 128, TDIM / 128), 256, 0, stream>>>(
      u_m, WdecT, enc, out, DDIM, HDIM);
}

// Round 3
// 299.082 us; speedup vs baseline: 8.2652x; 3.3679x over previous
//
#include <hip/hip_runtime.h>
#include <cmath>

#define NCC 151
#define NRCH 51
#define BDIM 32
#define NOBJ 100
#define DDIM 4096
#define HDIM 1024
#define TDIM (BDIM * NOBJ)   // 3200

typedef __bf16 bf16_t;
typedef __bf16 bf16x8 __attribute__((ext_vector_type(8)));
typedef __bf16 bf16x4 __attribute__((ext_vector_type(4)));
typedef float f32x4 __attribute__((ext_vector_type(4)));

// ---------------------------------------------------------------------------
// bf16 MFMA GEMM (m97 structure): C[M,N] = act(A[M,K] @ Bt[N,K]^T) (+ add)
// 128x128 tile, BK=64, 256 threads = 4 waves (2x2), 16x16x32 MFMA.
// XOR-swizzled LDS (rule #21: linear LDS dest + inverse-swizzled global src).
// ---------------------------------------------------------------------------
template <bool RELU, bool ADDF32OUT>
__global__ __launch_bounds__(256) void gemm_bf16(
    const bf16_t* __restrict__ A,   // [M][K] row-major
    const bf16_t* __restrict__ Bt,  // [N][K] row-major (pre-transposed weight)
    const float* __restrict__ add,  // fp32 residual when ADDF32OUT
    void* __restrict__ Cout,        // bf16 [M][N], or fp32 when ADDF32OUT
    int N, int K) {
  __shared__ __align__(16) bf16_t Asm[128 * 64];
  __shared__ __align__(16) bf16_t Bsm[128 * 64];
  const int tid = threadIdx.x;
  const int lane = tid & 63;
  const int w = tid >> 6;           // wave 0..3
  const int wm = w >> 1, wn = w & 1;
  const int bm = blockIdx.y * 128, bn = blockIdx.x * 128;
  const int lr = lane & 15;         // fragment row
  const int lk = lane >> 4;         // k sub-slot (0..3)

  f32x4 acc[4][4];
#pragma unroll
  for (int m = 0; m < 4; ++m)
#pragma unroll
    for (int n = 0; n < 4; ++n) acc[m][n] = (f32x4){0.f, 0.f, 0.f, 0.f};

  const int srow = tid >> 3;   // staging row within 32-row group
  const int sslot = tid & 7;   // staging 16B slot within row

  char* ldsA = (char*)Asm;
  char* ldsB = (char*)Bsm;

  for (int kt = 0; kt < K; kt += 64) {
    __syncthreads();
#pragma unroll
    for (int i = 0; i < 4; ++i) {
      const int row = i * 32 + srow;
      const int kc = sslot ^ (row & 7);
      const bf16_t* ga = A + (size_t)(bm + row) * K + kt + kc * 8;
      const bf16_t* gb = Bt + (size_t)(bn + row) * K + kt + kc * 8;
      __builtin_amdgcn_global_load_lds(
          (const __attribute__((address_space(1))) void*)ga,
          (__attribute__((address_space(3))) void*)(ldsA + i * 4096 + w * 1024),
          16, 0, 0);
      __builtin_amdgcn_global_load_lds(
          (const __attribute__((address_space(1))) void*)gb,
          (__attribute__((address_space(3))) void*)(ldsB + i * 4096 + w * 1024),
          16, 0, 0);
    }
    __syncthreads();

    bf16x8 af[4][2], bfr[4][2];
#pragma unroll
    for (int m = 0; m < 4; ++m) {
      const int row = wm * 64 + m * 16 + lr;
#pragma unroll
      for (int kk = 0; kk < 2; ++kk) {
        const int slot = kk * 4 + lk;
        af[m][kk] =
            *(const bf16x8*)(ldsA + row * 128 + ((slot ^ (lr & 7)) << 4));
      }
    }
#pragma unroll
    for (int n = 0; n < 4; ++n) {
      const int row = wn * 64 + n * 16 + lr;
#pragma unroll
      for (int kk = 0; kk < 2; ++kk) {
        const int slot = kk * 4 + lk;
        bfr[n][kk] =
            *(const bf16x8*)(ldsB + row * 128 + ((slot ^ (lr & 7)) << 4));
      }
    }
#pragma unroll
    for (int m = 0; m < 4; ++m)
#pragma unroll
      for (int n = 0; n < 4; ++n) {
        acc[m][n] = __builtin_amdgcn_mfma_f32_16x16x32_bf16(
            af[m][0], bfr[n][0], acc[m][n], 0, 0, 0);
        acc[m][n] = __builtin_amdgcn_mfma_f32_16x16x32_bf16(
            af[m][1], bfr[n][1], acc[m][n], 0, 0, 0);
      }
  }

  const int or0 = bm + wm * 64 + lk * 4;
  const int oc0 = bn + wn * 64 + lr;
#pragma unroll
  for (int m = 0; m < 4; ++m)
#pragma unroll
    for (int n = 0; n < 4; ++n)
#pragma unroll
      for (int r = 0; r < 4; ++r) {
        float v = acc[m][n][r];
        if (RELU) v = fmaxf(v, 0.f);
        const size_t off = (size_t)(or0 + m * 16 + r) * N + (oc0 + n * 16);
        if (ADDF32OUT)
          ((float*)Cout)[off] = v + add[off];
        else
          ((bf16_t*)Cout)[off] = (bf16_t)v;
      }
}

// ---------------------------------------------------------------------------
__global__ __launch_bounds__(256) void cvt_bf16_kernel(
    const float* __restrict__ in, bf16_t* __restrict__ out, int n4) {
  int i = blockIdx.x * 256 + threadIdx.x;
  if (i >= n4) return;
  float4 v = ((const float4*)in)[i];
  bf16x4 o = {(bf16_t)v.x, (bf16_t)v.y, (bf16_t)v.z, (bf16_t)v.w};
  ((bf16x4*)out)[i] = o;
}

// ---------------------------------------------------------------------------
// W[K][N] fp32 -> Wt[N][K] bf16, 32x32 LDS tile transpose
// ---------------------------------------------------------------------------
__global__ __launch_bounds__(256) void transT_kernel(
    const float* __restrict__ in, bf16_t* __restrict__ out, int K, int N) {
  __shared__ float t[32][33];
  const int n0 = blockIdx.x * 32, k0 = blockIdx.y * 32;
  const int tx = threadIdx.x & 31, ty = threadIdx.x >> 5;  // 32 x 8
#pragma unroll
  for (int i = 0; i < 4; ++i)
    t[ty + i * 8][tx] = in[(size_t)(k0 + ty + i * 8) * N + n0 + tx];
  __syncthreads();
#pragma unroll
  for (int i = 0; i < 4; ++i)
    out[(size_t)(n0 + ty + i * 8) * K + k0 + tx] = (bf16_t)t[tx][ty + i * 8];
}

// ---------------------------------------------------------------------------
// Conv chain, restructured algebraically:
//   conv1 is linear in channels -> precompute per-pair projection
//   femb1[p][k9][co] = sum_ci w1[co,ci,kh,kw] * femb[p][ci]
//   conv3 (1x1) folds into conv2: w23[k9][c2] = sum_c3 w3[c3]*w2[c3,c2,kh,kw]
// Rows padded 10 -> 12 floats for 16B-aligned float4 access.
// ---------------------------------------------------------------------------

// w1r[ci][k9][co] <- conv1w[co][ci][kh][kw]   (4590 elems)
__global__ __launch_bounds__(256) void prep_w1r_kernel(
    const float* __restrict__ w1, float* __restrict__ w1r) {
  int idx = blockIdx.x * 256 + threadIdx.x;
  if (idx >= NRCH * 90) return;
  int ci = idx / 90, r = idx % 90, k9 = r / 10, co = r % 10;
  w1r[idx] = w1[((co * NRCH + ci) * 3 + k9 / 3) * 3 + (k9 % 3)];
}

// w23[k9][c2] <- sum_c3 w3[c3] * w2[c3][c2][kh][kw]   (90 elems)
__global__ __launch_bounds__(128) void prep_w23_kernel(
    const float* __restrict__ w2, const float* __restrict__ w3,
    float* __restrict__ w23) {
  int t = threadIdx.x;
  if (t >= 90) return;
  int k9 = t / 10, c2 = t % 10;
  float acc = 0.f;
#pragma unroll
  for (int c3 = 0; c3 < 5; ++c3)
    acc += w3[c3] * w2[((c3 * 10 + c2) * 3 + k9 / 3) * 3 + (k9 % 3)];
  w23[t] = acc;
}

// pidx[b][i][j] = labels[b,i]*NCC + labels[b,j]
__global__ __launch_bounds__(256) void pidx_kernel(
    const int* __restrict__ preds, int* __restrict__ pidx) {
  int idx = blockIdx.x * 256 + threadIdx.x;
  if (idx >= BDIM * NOBJ * NOBJ) return;
  int j = idx % NOBJ;
  int i = (idx / NOBJ) % NOBJ;
  int b = idx / (NOBJ * NOBJ);
  pidx[idx] = preds[b * NOBJ + i] * NCC + preds[b * NOBJ + j];
}

// femb1[p][k9][0..9] (stride 12) = sum_ci femb[p][ci] * w1r[ci][k9co]
__global__ __launch_bounds__(128) void femb1_kernel(
    const float* __restrict__ femb, const float* __restrict__ w1r,
    float* __restrict__ femb1) {
  __shared__ float row[NRCH];
  const int p = blockIdx.x;
  if (threadIdx.x < NRCH)
    row[threadIdx.x] = femb[(size_t)p * NRCH + threadIdx.x];
  __syncthreads();
  const int t = threadIdx.x;
  if (t >= 90) return;
  float acc = 0.f;
#pragma unroll
  for (int ci = 0; ci < NRCH; ++ci) acc += row[ci] * w1r[ci * 90 + t];
  femb1[((size_t)p * 9 + t / 10) * 12 + (t % 10)] = acc;
}

// x1[b][i][j][0..9] (stride 12) = sum over valid 3x3 neighbors of
//   femb1[pidx[b][ii][jj]][k9][*]
__global__ __launch_bounds__(256) void conv1g_kernel(
    const int* __restrict__ pidx, const float* __restrict__ femb1,
    float* __restrict__ x1) {
  int idx = blockIdx.x * 256 + threadIdx.x;
  if (idx >= BDIM * NOBJ * NOBJ) return;
  int j = idx % NOBJ;
  int i = (idx / NOBJ) % NOBJ;
  int b = idx / (NOBJ * NOBJ);
  f32x4 a0 = {0.f, 0.f, 0.f, 0.f}, a1 = a0, a2 = a0;
  const int* pb = pidx + b * NOBJ * NOBJ;
#pragma unroll
  for (int kh = 0; kh < 3; ++kh) {
    int ii = i + kh - 1;
    if (ii < 0 || ii >= NOBJ) continue;
#pragma unroll
    for (int kw = 0; kw < 3; ++kw) {
      int jj = j + kw - 1;
      if (jj < 0 || jj >= NOBJ) continue;
      int p = pb[ii * NOBJ + jj];
      const f32x4* f =
          (const f32x4*)(femb1 + ((size_t)p * 9 + kh * 3 + kw) * 12);
      a0 += f[0];
      a1 += f[1];
      a2 += f[2];
    }
  }
  f32x4* o = (f32x4*)(x1 + (size_t)idx * 12);
  o[0] = a0;
  o[1] = a1;
  o[2] = a2;
}

// adj[b][i][j] = tanh(sum over valid 3x3 of dot(w23[k9][*], x1[b][ii][jj][*]))
__global__ __launch_bounds__(256) void conv23_kernel(
    const float* __restrict__ x1, const float* __restrict__ w23,
    float* __restrict__ adj) {
  __shared__ float w[90];
  if (threadIdx.x < 90) w[threadIdx.x] = w23[threadIdx.x];
  __syncthreads();
  int idx = blockIdx.x * 256 + threadIdx.x;
  if (idx >= BDIM * NOBJ * NOBJ) return;
  int j = idx % NOBJ;
  int i = (idx / NOBJ) % NOBJ;
  int b = idx / (NOBJ * NOBJ);
  float acc = 0.f;
  const float* xb = x1 + (size_t)b * NOBJ * NOBJ * 12;
#pragma unroll
  for (int kh = 0; kh < 3; ++kh) {
    int ii = i + kh - 1;
    if (ii < 0 || ii >= NOBJ) continue;
#pragma unroll
    for (int kw = 0; kw < 3; ++kw) {
      int jj = j + kw - 1;
      if (jj < 0 || jj >= NOBJ) continue;
      const float* xr = xb + (ii * NOBJ + jj) * 12;
      const float* wr = w + (kh * 3 + kw) * 10;
#pragma unroll
      for (int c = 0; c < 10; ++c) acc += wr[c] * xr[c];
    }
  }
  adj[idx] = tanhf(acc);
}

// ---------------------------------------------------------------------------
// einsum: ofl_u[b,n,h] = sum_m adj[b,n,m] * obj_u1[b,m,h]  (bf16 in/out)
// ---------------------------------------------------------------------------
__global__ __launch_bounds__(256) void einsum_kernel(
    const float* __restrict__ adj, const bf16_t* __restrict__ u1,
    bf16_t* __restrict__ out) {
  int b = blockIdx.x / NOBJ;
  int n = blockIdx.x % NOBJ;
  __shared__ float arow[NOBJ];
  if (threadIdx.x < NOBJ)
    arow[threadIdx.x] = adj[((size_t)b * NOBJ + n) * NOBJ + threadIdx.x];
  __syncthreads();
  const bf16_t* ub = u1 + (size_t)b * NOBJ * HDIM;
  const int h0 = threadIdx.x * 4;
  float a0 = 0.f, a1 = 0.f, a2 = 0.f, a3 = 0.f;
  for (int m = 0; m < NOBJ; ++m) {
    float a = arow[m];
    bf16x4 v = *(const bf16x4*)(ub + (size_t)m * HDIM + h0);
    a0 += a * (float)v[0];
    a1 += a * (float)v[1];
    a2 += a * (float)v[2];
    a3 += a * (float)v[3];
  }
  bf16x4 o = {(bf16_t)a0, (bf16_t)a1, (bf16_t)a2, (bf16_t)a3};
  *(bf16x4*)(out + ((size_t)b * NOBJ + n) * HDIM + h0) = o;
}

// ---------------------------------------------------------------------------
extern "C" void kernel_launch(void* const* d_in, const int* in_sizes, int n_in,
                              void* d_out, int out_size, void* d_ws,
                              size_t ws_size, hipStream_t stream) {
  const float* enc = (const float*)d_in[0];
  const float* W_comp = (const float*)d_in[1];
  const float* W_ou1 = (const float*)d_in[2];
  const float* W_ofc = (const float*)d_in[3];
  const float* W_dec = (const float*)d_in[4];
  const float* conv1w = (const float*)d_in[5];
  const float* conv2w = (const float*)d_in[6];
  const float* conv3w = (const float*)d_in[7];
  const float* femb = (const float*)d_in[8];
  const int* preds = (const int*)d_in[9];
  float* out = (float*)d_out;
  char* wsb = (char*)d_ws;

  // workspace (bytes):
  // phase A [0, 43.25M): encb / WcompT / Wou1T / comp (dead after GEMM2)
  // phase C [0, 23.6M): ofl_u / WofcT / u_m / WdecT   (after conv chain)
  // conv region [43.25M, 77.6M): persists across phase A->C boundary only
  // where needed (obj_u1, adj survive until einsum/GEMM3).
  bf16_t* encb   = (bf16_t*)(wsb + 0);           // 26,214,400
  bf16_t* WcompT = (bf16_t*)(wsb + 26214400);    //  8,388,608
  bf16_t* Wou1T  = (bf16_t*)(wsb + 34603008);    //  2,097,152
  bf16_t* comp   = (bf16_t*)(wsb + 36700160);    //  6,553,600 (ends 43.25M)
  float*  w1r    = (float*)(wsb + 43253760);     //     18,360
  float*  w23    = (float*)(wsb + 43272128);     //        360
  float*  femb1  = (float*)(wsb + 43272512);     //  9,850,032
  int*    pidx   = (int*)(wsb + 53122560);       //  1,280,000
  float*  x1     = (float*)(wsb + 54402560);     // 15,360,000
  bf16_t* obj_u1 = (bf16_t*)(wsb + 69762560);    //  6,553,600
  float*  adj    = (float*)(wsb + 76316160);     //  1,280,000 (ends 77.6M)
  bf16_t* ofl_u  = (bf16_t*)(wsb + 0);           //  6,553,600
  bf16_t* WofcT  = (bf16_t*)(wsb + 6553600);     //  2,097,152
  bf16_t* u_m    = (bf16_t*)(wsb + 8650752);     //  6,553,600
  bf16_t* WdecT  = (bf16_t*)(wsb + 15204352);    //  8,388,608 (ends 23.6M)

  // --- conversions for GEMM1/2 ---
  cvt_bf16_kernel<<<(TDIM * DDIM / 4 + 255) / 256, 256, 0, stream>>>(
      enc, encb, TDIM * DDIM / 4);
  transT_kernel<<<dim3(HDIM / 32, DDIM / 32), 256, 0, stream>>>(
      W_comp, WcompT, DDIM, HDIM);
  transT_kernel<<<dim3(HDIM / 32, HDIM / 32), 256, 0, stream>>>(
      W_ou1, Wou1T, HDIM, HDIM);

  // 1. comp = relu(enc @ W_comp)   M=3200 N=1024 K=4096
  gemm_bf16<true, false><<<dim3(HDIM / 128, TDIM / 128), 256, 0, stream>>>(
      encb, WcompT, nullptr, comp, HDIM, DDIM);
  // 2. obj_u1 = relu(comp @ W_ou1) M=3200 N=1024 K=1024
  gemm_bf16<true, false><<<dim3(HDIM / 128, TDIM / 128), 256, 0, stream>>>(
      comp, Wou1T, nullptr, obj_u1, HDIM, HDIM);

  // 3. conv chain precomputes
  prep_w1r_kernel<<<(NRCH * 90 + 255) / 256, 256, 0, stream>>>(conv1w, w1r);
  prep_w23_kernel<<<1, 128, 0, stream>>>(conv2w, conv3w, w23);
  pidx_kernel<<<(BDIM * NOBJ * NOBJ + 255) / 256, 256, 0, stream>>>(preds,
                                                                    pidx);
  femb1_kernel<<<NCC * NCC, 128, 0, stream>>>(femb, w1r, femb1);

  // 4. conv1 via gather-sum of projected pair features
  conv1g_kernel<<<(BDIM * NOBJ * NOBJ + 255) / 256, 256, 0, stream>>>(
      pidx, femb1, x1);
  // 5. conv2+conv3+tanh fused
  conv23_kernel<<<(BDIM * NOBJ * NOBJ + 255) / 256, 256, 0, stream>>>(x1, w23,
                                                                      adj);

  // conversions for GEMM3/4 (phase-A region is dead now)
  transT_kernel<<<dim3(HDIM / 32, HDIM / 32), 256, 0, stream>>>(
      W_ofc, WofcT, HDIM, HDIM);
  transT_kernel<<<dim3(DDIM / 32, HDIM / 32), 256, 0, stream>>>(
      W_dec, WdecT, HDIM, DDIM);

  // 7. einsum -> ofl_u (bf16)
  einsum_kernel<<<BDIM * NOBJ, 256, 0, stream>>>(adj, obj_u1, ofl_u);

  // 8. u_m = relu(ofl_u @ W_ofc)   M=3200 N=1024 K=1024
  gemm_bf16<true, false><<<dim3(HDIM / 128, TDIM / 128), 256, 0, stream>>>(
      ofl_u, WofcT, nullptr, u_m, HDIM, HDIM);
  // 9. out = relu(u_m @ W_dec) + enc   M=3200 N=4096 K=1024  (fp32 out)
  gemm_bf16<true, true><<<dim3(DDIM / 128, TDIM / 128), 256, 0, stream>>>(
      u_m, WdecT, enc, out, DDIM, HDIM);
}

// Round 4
// 289.439 us; speedup vs baseline: 8.5405x; 1.0333x over previous
//
#include <hip/hip_runtime.h>
#include <cmath>

#define NCC 151
#define NRCH 51
#define BDIM 32
#define NOBJ 100
#define DDIM 4096
#define HDIM 1024
#define TDIM (BDIM * NOBJ)   // 3200

typedef __bf16 bf16_t;
typedef __bf16 bf16x8 __attribute__((ext_vector_type(8)));
typedef __bf16 bf16x4 __attribute__((ext_vector_type(4)));
typedef float f32x4 __attribute__((ext_vector_type(4)));

// ---------------------------------------------------------------------------
// bf16 MFMA GEMM (m97 structure): C[M,N] = act(A[M,K] @ Bt[N,K]^T) (+ add)
// 128x128 tile, BK=64, 256 threads = 4 waves (2x2), 16x16x32 MFMA.
// XOR-swizzled LDS (rule #21). Bijective XCD-chunked blockIdx swizzle (T1,
// m204) — all grids here have nwg % 8 == 0.
// SPLITK>1: blockIdx.z selects a K-chunk (rounded to 64); block writes fp32
// partial (no act) to Cout + z*MN; a reduce kernel finishes relu+cvt.
// ---------------------------------------------------------------------------
template <bool RELU, bool ADDF32OUT, int SPLITK>
__global__ __launch_bounds__(256) void gemm_bf16(
    const bf16_t* __restrict__ A,   // [M][K] row-major
    const bf16_t* __restrict__ Bt,  // [N][K] row-major (pre-transposed weight)
    const float* __restrict__ add,  // fp32 residual when ADDF32OUT
    void* __restrict__ Cout,        // bf16 [M][N]; fp32 if ADDF32OUT/partial
    int N, int K, size_t MN) {
  __shared__ __align__(16) bf16_t Asm[128 * 64];
  __shared__ __align__(16) bf16_t Bsm[128 * 64];
  const int tid = threadIdx.x;
  const int lane = tid & 63;
  const int w = tid >> 6;           // wave 0..3
  const int wm = w >> 1, wn = w & 1;

  // XCD-chunked bijective swizzle over the flattened grid
  const int nx = gridDim.x, ny = gridDim.y;
  int lin = blockIdx.x + nx * (blockIdx.y + ny * blockIdx.z);
  const int nwg = nx * ny * gridDim.z;
  const int q = nwg >> 3;
  lin = (lin & 7) * q + (lin >> 3);
  const int bx = lin % nx;
  const int r2 = lin / nx;
  const int by = r2 % ny;
  const int bz = r2 / ny;

  const int bm = by * 128, bn = bx * 128;
  const int lr = lane & 15;         // fragment row
  const int lk = lane >> 4;         // k sub-slot (0..3)

  // K range for this split
  int kBeg = 0, kEnd = K;
  if (SPLITK > 1) {
    const int chunk = (((K / 64) + SPLITK - 1) / SPLITK) * 64;
    kBeg = bz * chunk;
    kEnd = min(K, kBeg + chunk);
  }

  f32x4 acc[4][4];
#pragma unroll
  for (int m = 0; m < 4; ++m)
#pragma unroll
    for (int n = 0; n < 4; ++n) acc[m][n] = (f32x4){0.f, 0.f, 0.f, 0.f};

  const int srow = tid >> 3;   // staging row within 32-row group
  const int sslot = tid & 7;   // staging 16B slot within row

  char* ldsA = (char*)Asm;
  char* ldsB = (char*)Bsm;

  for (int kt = kBeg; kt < kEnd; kt += 64) {
    __syncthreads();
#pragma unroll
    for (int i = 0; i < 4; ++i) {
      const int row = i * 32 + srow;
      const int kc = sslot ^ (row & 7);
      const bf16_t* ga = A + (size_t)(bm + row) * K + kt + kc * 8;
      const bf16_t* gb = Bt + (size_t)(bn + row) * K + kt + kc * 8;
      __builtin_amdgcn_global_load_lds(
          (const __attribute__((address_space(1))) void*)ga,
          (__attribute__((address_space(3))) void*)(ldsA + i * 4096 + w * 1024),
          16, 0, 0);
      __builtin_amdgcn_global_load_lds(
          (const __attribute__((address_space(1))) void*)gb,
          (__attribute__((address_space(3))) void*)(ldsB + i * 4096 + w * 1024),
          16, 0, 0);
    }
    __syncthreads();

    bf16x8 af[4][2], bfr[4][2];
#pragma unroll
    for (int m = 0; m < 4; ++m) {
      const int row = wm * 64 + m * 16 + lr;
#pragma unroll
      for (int kk = 0; kk < 2; ++kk) {
        const int slot = kk * 4 + lk;
        af[m][kk] =
            *(const bf16x8*)(ldsA + row * 128 + ((slot ^ (lr & 7)) << 4));
      }
    }
#pragma unroll
    for (int n = 0; n < 4; ++n) {
      const int row = wn * 64 + n * 16 + lr;
#pragma unroll
      for (int kk = 0; kk < 2; ++kk) {
        const int slot = kk * 4 + lk;
        bfr[n][kk] =
            *(const bf16x8*)(ldsB + row * 128 + ((slot ^ (lr & 7)) << 4));
      }
    }
#pragma unroll
    for (int m = 0; m < 4; ++m)
#pragma unroll
      for (int n = 0; n < 4; ++n) {
        acc[m][n] = __builtin_amdgcn_mfma_f32_16x16x32_bf16(
            af[m][0], bfr[n][0], acc[m][n], 0, 0, 0);
        acc[m][n] = __builtin_amdgcn_mfma_f32_16x16x32_bf16(
            af[m][1], bfr[n][1], acc[m][n], 0, 0, 0);
      }
  }

  const int or0 = bm + wm * 64 + lk * 4;
  const int oc0 = bn + wn * 64 + lr;
#pragma unroll
  for (int m = 0; m < 4; ++m)
#pragma unroll
    for (int n = 0; n < 4; ++n)
#pragma unroll
      for (int r = 0; r < 4; ++r) {
        float v = acc[m][n][r];
        const size_t off = (size_t)(or0 + m * 16 + r) * N + (oc0 + n * 16);
        if (SPLITK > 1) {
          ((float*)Cout)[bz * MN + off] = v;  // raw partial
        } else {
          if (RELU) v = fmaxf(v, 0.f);
          if (ADDF32OUT)
            ((float*)Cout)[off] = v + add[off];
          else
            ((bf16_t*)Cout)[off] = (bf16_t)v;
        }
      }
}

// reduce 3 fp32 partials -> relu -> bf16
__global__ __launch_bounds__(256) void reduce3_kernel(
    const float* __restrict__ p, bf16_t* __restrict__ out, int n4) {
  int i = blockIdx.x * 256 + threadIdx.x;
  if (i >= n4) return;
  const f32x4* pv = (const f32x4*)p;
  f32x4 v = pv[i] + pv[i + n4] + pv[i + 2 * (size_t)n4];
  bf16x4 o = {(bf16_t)fmaxf(v[0], 0.f), (bf16_t)fmaxf(v[1], 0.f),
              (bf16_t)fmaxf(v[2], 0.f), (bf16_t)fmaxf(v[3], 0.f)};
  ((bf16x4*)out)[i] = o;
}

// ---------------------------------------------------------------------------
__global__ __launch_bounds__(256) void cvt_bf16_kernel(
    const float* __restrict__ in, bf16_t* __restrict__ out, int n4) {
  int i = blockIdx.x * 256 + threadIdx.x;
  if (i >= n4) return;
  float4 v = ((const float4*)in)[i];
  bf16x4 o = {(bf16_t)v.x, (bf16_t)v.y, (bf16_t)v.z, (bf16_t)v.w};
  ((bf16x4*)out)[i] = o;
}

// ---------------------------------------------------------------------------
// W[K][N] fp32 -> Wt[N][K] bf16, 32x32 LDS tile transpose
// ---------------------------------------------------------------------------
__global__ __launch_bounds__(256) void transT_kernel(
    const float* __restrict__ in, bf16_t* __restrict__ out, int K, int N) {
  __shared__ float t[32][33];
  const int n0 = blockIdx.x * 32, k0 = blockIdx.y * 32;
  const int tx = threadIdx.x & 31, ty = threadIdx.x >> 5;  // 32 x 8
#pragma unroll
  for (int i = 0; i < 4; ++i)
    t[ty + i * 8][tx] = in[(size_t)(k0 + ty + i * 8) * N + n0 + tx];
  __syncthreads();
#pragma unroll
  for (int i = 0; i < 4; ++i)
    out[(size_t)(n0 + ty + i * 8) * K + k0 + tx] = (bf16_t)t[tx][ty + i * 8];
}

// ---------------------------------------------------------------------------
// Conv chain (algebraically restructured; see R2 notes):
//   femb1[p][k9][co] = sum_ci w1[co,ci,kh,kw]*femb[p][ci]; conv3 folded in w23.
// ---------------------------------------------------------------------------
__global__ __launch_bounds__(256) void prep_w1r_kernel(
    const float* __restrict__ w1, float* __restrict__ w1r) {
  int idx = blockIdx.x * 256 + threadIdx.x;
  if (idx >= NRCH * 90) return;
  int ci = idx / 90, r = idx % 90, k9 = r / 10, co = r % 10;
  w1r[idx] = w1[((co * NRCH + ci) * 3 + k9 / 3) * 3 + (k9 % 3)];
}

__global__ __launch_bounds__(128) void prep_w23_kernel(
    const float* __restrict__ w2, const float* __restrict__ w3,
    float* __restrict__ w23) {
  int t = threadIdx.x;
  if (t >= 90) return;
  int k9 = t / 10, c2 = t % 10;
  float acc = 0.f;
#pragma unroll
  for (int c3 = 0; c3 < 5; ++c3)
    acc += w3[c3] * w2[((c3 * 10 + c2) * 3 + k9 / 3) * 3 + (k9 % 3)];
  w23[t] = acc;
}

__global__ __launch_bounds__(256) void pidx_kernel(
    const int* __restrict__ preds, int* __restrict__ pidx) {
  int idx = blockIdx.x * 256 + threadIdx.x;
  if (idx >= BDIM * NOBJ * NOBJ) return;
  int j = idx % NOBJ;
  int i = (idx / NOBJ) % NOBJ;
  int b = idx / (NOBJ * NOBJ);
  pidx[idx] = preds[b * NOBJ + i] * NCC + preds[b * NOBJ + j];
}

__global__ __launch_bounds__(128) void femb1_kernel(
    const float* __restrict__ femb, const float* __restrict__ w1r,
    float* __restrict__ femb1) {
  __shared__ float row[NRCH];
  const int p = blockIdx.x;
  if (threadIdx.x < NRCH)
    row[threadIdx.x] = femb[(size_t)p * NRCH + threadIdx.x];
  __syncthreads();
  const int t = threadIdx.x;
  if (t >= 90) return;
  float acc = 0.f;
#pragma unroll
  for (int ci = 0; ci < NRCH; ++ci) acc += row[ci] * w1r[ci * 90 + t];
  femb1[((size_t)p * 9 + t / 10) * 12 + (t % 10)] = acc;
}

__global__ __launch_bounds__(256) void conv1g_kernel(
    const int* __restrict__ pidx, const float* __restrict__ femb1,
    float* __restrict__ x1) {
  int idx = blockIdx.x * 256 + threadIdx.x;
  if (idx >= BDIM * NOBJ * NOBJ) return;
  int j = idx % NOBJ;
  int i = (idx / NOBJ) % NOBJ;
  int b = idx / (NOBJ * NOBJ);
  f32x4 a0 = {0.f, 0.f, 0.f, 0.f}, a1 = a0, a2 = a0;
  const int* pb = pidx + b * NOBJ * NOBJ;
#pragma unroll
  for (int kh = 0; kh < 3; ++kh) {
    int ii = i + kh - 1;
    if (ii < 0 || ii >= NOBJ) continue;
#pragma unroll
    for (int kw = 0; kw < 3; ++kw) {
      int jj = j + kw - 1;
      if (jj < 0 || jj >= NOBJ) continue;
      int p = pb[ii * NOBJ + jj];
      const f32x4* f =
          (const f32x4*)(femb1 + ((size_t)p * 9 + kh * 3 + kw) * 12);
      a0 += f[0];
      a1 += f[1];
      a2 += f[2];
    }
  }
  f32x4* o = (f32x4*)(x1 + (size_t)idx * 12);
  o[0] = a0;
  o[1] = a1;
  o[2] = a2;
}

__global__ __launch_bounds__(256) void conv23_kernel(
    const float* __restrict__ x1, const float* __restrict__ w23,
    float* __restrict__ adj) {
  __shared__ float w[90];
  if (threadIdx.x < 90) w[threadIdx.x] = w23[threadIdx.x];
  __syncthreads();
  int idx = blockIdx.x * 256 + threadIdx.x;
  if (idx >= BDIM * NOBJ * NOBJ) return;
  int j = idx % NOBJ;
  int i = (idx / NOBJ) % NOBJ;
  int b = idx / (NOBJ * NOBJ);
  float acc = 0.f;
  const float* xb = x1 + (size_t)b * NOBJ * NOBJ * 12;
#pragma unroll
  for (int kh = 0; kh < 3; ++kh) {
    int ii = i + kh - 1;
    if (ii < 0 || ii >= NOBJ) continue;
#pragma unroll
    for (int kw = 0; kw < 3; ++kw) {
      int jj = j + kw - 1;
      if (jj < 0 || jj >= NOBJ) continue;
      const float* xr = xb + (ii * NOBJ + jj) * 12;
      const float* wr = w + (kh * 3 + kw) * 10;
#pragma unroll
      for (int c = 0; c < 10; ++c) acc += wr[c] * xr[c];
    }
  }
  adj[idx] = tanhf(acc);
}

// ---------------------------------------------------------------------------
// einsum: ofl_u[b,n,h] = sum_m adj[b,n,m] * obj_u1[b,m,h]  (bf16 in/out)
// ---------------------------------------------------------------------------
__global__ __launch_bounds__(256) void einsum_kernel(
    const float* __restrict__ adj, const bf16_t* __restrict__ u1,
    bf16_t* __restrict__ out) {
  int b = blockIdx.x / NOBJ;
  int n = blockIdx.x % NOBJ;
  __shared__ float arow[NOBJ];
  if (threadIdx.x < NOBJ)
    arow[threadIdx.x] = adj[((size_t)b * NOBJ + n) * NOBJ + threadIdx.x];
  __syncthreads();
  const bf16_t* ub = u1 + (size_t)b * NOBJ * HDIM;
  const int h0 = threadIdx.x * 4;
  float a0 = 0.f, a1 = 0.f, a2 = 0.f, a3 = 0.f;
  for (int m = 0; m < NOBJ; ++m) {
    float a = arow[m];
    bf16x4 v = *(const bf16x4*)(ub + (size_t)m * HDIM + h0);
    a0 += a * (float)v[0];
    a1 += a * (float)v[1];
    a2 += a * (float)v[2];
    a3 += a * (float)v[3];
  }
  bf16x4 o = {(bf16_t)a0, (bf16_t)a1, (bf16_t)a2, (bf16_t)a3};
  *(bf16x4*)(out + ((size_t)b * NOBJ + n) * HDIM + h0) = o;
}

// ---------------------------------------------------------------------------
extern "C" void kernel_launch(void* const* d_in, const int* in_sizes, int n_in,
                              void* d_out, int out_size, void* d_ws,
                              size_t ws_size, hipStream_t stream) {
  const float* enc = (const float*)d_in[0];
  const float* W_comp = (const float*)d_in[1];
  const float* W_ou1 = (const float*)d_in[2];
  const float* W_ofc = (const float*)d_in[3];
  const float* W_dec = (const float*)d_in[4];
  const float* conv1w = (const float*)d_in[5];
  const float* conv2w = (const float*)d_in[6];
  const float* conv3w = (const float*)d_in[7];
  const float* femb = (const float*)d_in[8];
  const int* preds = (const int*)d_in[9];
  float* out = (float*)d_out;
  char* wsb = (char*)d_ws;

  const size_t MN = (size_t)TDIM * HDIM;  // 3,276,800

  // workspace (bytes), peak 80.5MB (proven budget >= 92.3MB from R1):
  // G1 phase: encb[0,26.2M) WcompT[26.2,34.6M) comp[34.6,41.16M)
  //           part3[41.16M, 80.48M)  (3 x 13.1MB fp32 partials)
  // after reduce: Wou1T reuses part area [41.16M, 43.25M)
  // conv region [43.25M, 77.6M) as before (partials dead by then)
  // phase C [0, 23.6M): ofl_u / WofcT / u_m / WdecT
  bf16_t* encb   = (bf16_t*)(wsb + 0);           // 26,214,400
  bf16_t* WcompT = (bf16_t*)(wsb + 26214400);    //  8,388,608
  bf16_t* comp   = (bf16_t*)(wsb + 34603008);    //  6,553,600
  float*  part3  = (float*)(wsb + 41156608);     // 39,321,600 (ends 80.48M)
  bf16_t* Wou1T  = (bf16_t*)(wsb + 41156608);    //  2,097,152 (after reduce)
  float*  w1r    = (float*)(wsb + 43253760);     //     18,360
  float*  w23    = (float*)(wsb + 43272128);     //        360
  float*  femb1  = (float*)(wsb + 43272512);     //  9,850,032
  int*    pidx   = (int*)(wsb + 53122560);       //  1,280,000
  float*  x1     = (float*)(wsb + 54402560);     // 15,360,000
  bf16_t* obj_u1 = (bf16_t*)(wsb + 69762560);    //  6,553,600
  float*  adj    = (float*)(wsb + 76316160);     //  1,280,000 (ends 77.6M)
  bf16_t* ofl_u  = (bf16_t*)(wsb + 0);           //  6,553,600
  bf16_t* WofcT  = (bf16_t*)(wsb + 6553600);     //  2,097,152
  bf16_t* u_m    = (bf16_t*)(wsb + 8650752);     //  6,553,600
  bf16_t* WdecT  = (bf16_t*)(wsb + 15204352);    //  8,388,608 (ends 23.6M)

  // --- conversions for GEMM1 ---
  cvt_bf16_kernel<<<(TDIM * DDIM / 4 + 255) / 256, 256, 0, stream>>>(
      enc, encb, TDIM * DDIM / 4);
  transT_kernel<<<dim3(HDIM / 32, DDIM / 32), 256, 0, stream>>>(
      W_comp, WcompT, DDIM, HDIM);

  // 1. comp = relu(enc @ W_comp)   M=3200 N=1024 K=4096, split-K=3
  gemm_bf16<false, false, 3>
      <<<dim3(HDIM / 128, TDIM / 128, 3), 256, 0, stream>>>(
          encb, WcompT, nullptr, part3, HDIM, DDIM, MN);
  reduce3_kernel<<<(int)(MN / 4 / 256), 256, 0, stream>>>(part3, comp,
                                                          (int)(MN / 4));

  // 2. obj_u1 = relu(comp @ W_ou1) M=3200 N=1024 K=1024
  transT_kernel<<<dim3(HDIM / 32, HDIM / 32), 256, 0, stream>>>(
      W_ou1, Wou1T, HDIM, HDIM);
  gemm_bf16<true, false, 1>
      <<<dim3(HDIM / 128, TDIM / 128), 256, 0, stream>>>(
          comp, Wou1T, nullptr, obj_u1, HDIM, HDIM, MN);

  // 3. conv chain precomputes
  prep_w1r_kernel<<<(NRCH * 90 + 255) / 256, 256, 0, stream>>>(conv1w, w1r);
  prep_w23_kernel<<<1, 128, 0, stream>>>(conv2w, conv3w, w23);
  pidx_kernel<<<(BDIM * NOBJ * NOBJ + 255) / 256, 256, 0, stream>>>(preds,
                                                                    pidx);
  femb1_kernel<<<NCC * NCC, 128, 0, stream>>>(femb, w1r, femb1);

  // 4. conv1 via gather-sum; 5. conv2+conv3+tanh fused
  conv1g_kernel<<<(BDIM * NOBJ * NOBJ + 255) / 256, 256, 0, stream>>>(
      pidx, femb1, x1);
  conv23_kernel<<<(BDIM * NOBJ * NOBJ + 255) / 256, 256, 0, stream>>>(x1, w23,
                                                                      adj);

  // conversions for GEMM3/4 (phase-A region dead now)
  transT_kernel<<<dim3(HDIM / 32, HDIM / 32), 256, 0, stream>>>(
      W_ofc, WofcT, HDIM, HDIM);
  transT_kernel<<<dim3(DDIM / 32, HDIM / 32), 256, 0, stream>>>(
      W_dec, WdecT, HDIM, DDIM);

  // 7. einsum -> ofl_u (bf16)
  einsum_kernel<<<BDIM * NOBJ, 256, 0, stream>>>(adj, obj_u1, ofl_u);

  // 8. u_m = relu(ofl_u @ W_ofc)   M=3200 N=1024 K=1024
  gemm_bf16<true, false, 1>
      <<<dim3(HDIM / 128, TDIM / 128), 256, 0, stream>>>(
          ofl_u, WofcT, nullptr, u_m, HDIM, HDIM, MN);
  // 9. out = relu(u_m @ W_dec) + enc   M=3200 N=4096 K=1024  (fp32 out)
  gemm_bf16<true, true, 1>
      <<<dim3(DDIM / 128, TDIM / 128), 256, 0, stream>>>(
          u_m, WdecT, enc, out, DDIM, HDIM, MN);
}

// Round 5
// 244.042 us; speedup vs baseline: 10.1293x; 1.1860x over previous
//
#include <hip/hip_runtime.h>
#include <cmath>

#define NCC 151
#define NRCH 51
#define BDIM 32
#define NOBJ 100
#define DDIM 4096
#define HDIM 1024
#define TDIM (BDIM * NOBJ)   // 3200

typedef __bf16 bf16_t;
typedef __bf16 bf16x8 __attribute__((ext_vector_type(8)));
typedef __bf16 bf16x4 __attribute__((ext_vector_type(4)));
typedef float f32x4 __attribute__((ext_vector_type(4)));

// ---------------------------------------------------------------------------
// bf16 MFMA GEMM (m97 structure): C[M,N] = act(A[M,K] @ Bt[N,K]^T) (+ add)
// 128x128 tile, BK=64, 256 threads = 4 waves (2x2), 16x16x32 MFMA.
// XOR-swizzled LDS (rule #21). Bijective XCD-chunked blockIdx swizzle.
// SPLITK>1: blockIdx.z selects a K-chunk; block writes bf16 partial to
// Cout + z*MN; reduce6_kernel finishes sum+relu.
// ---------------------------------------------------------------------------
template <bool RELU, bool ADDF32OUT, int SPLITK>
__global__ __launch_bounds__(256) void gemm_bf16(
    const bf16_t* __restrict__ A,   // [M][K] row-major
    const bf16_t* __restrict__ Bt,  // [N][K] row-major (pre-transposed weight)
    const float* __restrict__ add,  // fp32 residual when ADDF32OUT
    void* __restrict__ Cout,        // bf16 [M][N]; fp32 if ADDF32OUT
    int N, int K, size_t MN) {
  __shared__ __align__(16) bf16_t Asm[128 * 64];
  __shared__ __align__(16) bf16_t Bsm[128 * 64];
  const int tid = threadIdx.x;
  const int lane = tid & 63;
  const int w = tid >> 6;           // wave 0..3
  const int wm = w >> 1, wn = w & 1;

  // XCD-chunked bijective swizzle over the flattened grid (nwg % 8 == 0)
  const int nx = gridDim.x, ny = gridDim.y;
  int lin = blockIdx.x + nx * (blockIdx.y + ny * blockIdx.z);
  const int nwg = nx * ny * gridDim.z;
  const int q = nwg >> 3;
  lin = (lin & 7) * q + (lin >> 3);
  const int bx = lin % nx;
  const int r2 = lin / nx;
  const int by = r2 % ny;
  const int bz = r2 / ny;

  const int bm = by * 128, bn = bx * 128;
  const int lr = lane & 15;         // fragment row
  const int lk = lane >> 4;         // k sub-slot (0..3)

  int kBeg = 0, kEnd = K;
  if (SPLITK > 1) {
    const int chunk = (((K / 64) + SPLITK - 1) / SPLITK) * 64;
    kBeg = bz * chunk;
    kEnd = min(K, kBeg + chunk);
  }

  f32x4 acc[4][4];
#pragma unroll
  for (int m = 0; m < 4; ++m)
#pragma unroll
    for (int n = 0; n < 4; ++n) acc[m][n] = (f32x4){0.f, 0.f, 0.f, 0.f};

  const int srow = tid >> 3;   // staging row within 32-row group
  const int sslot = tid & 7;   // staging 16B slot within row

  char* ldsA = (char*)Asm;
  char* ldsB = (char*)Bsm;

  for (int kt = kBeg; kt < kEnd; kt += 64) {
    __syncthreads();
#pragma unroll
    for (int i = 0; i < 4; ++i) {
      const int row = i * 32 + srow;
      const int kc = sslot ^ (row & 7);
      const bf16_t* ga = A + (size_t)(bm + row) * K + kt + kc * 8;
      const bf16_t* gb = Bt + (size_t)(bn + row) * K + kt + kc * 8;
      __builtin_amdgcn_global_load_lds(
          (const __attribute__((address_space(1))) void*)ga,
          (__attribute__((address_space(3))) void*)(ldsA + i * 4096 + w * 1024),
          16, 0, 0);
      __builtin_amdgcn_global_load_lds(
          (const __attribute__((address_space(1))) void*)gb,
          (__attribute__((address_space(3))) void*)(ldsB + i * 4096 + w * 1024),
          16, 0, 0);
    }
    __syncthreads();

    bf16x8 af[4][2], bfr[4][2];
#pragma unroll
    for (int m = 0; m < 4; ++m) {
      const int row = wm * 64 + m * 16 + lr;
#pragma unroll
      for (int kk = 0; kk < 2; ++kk) {
        const int slot = kk * 4 + lk;
        af[m][kk] =
            *(const bf16x8*)(ldsA + row * 128 + ((slot ^ (lr & 7)) << 4));
      }
    }
#pragma unroll
    for (int n = 0; n < 4; ++n) {
      const int row = wn * 64 + n * 16 + lr;
#pragma unroll
      for (int kk = 0; kk < 2; ++kk) {
        const int slot = kk * 4 + lk;
        bfr[n][kk] =
            *(const bf16x8*)(ldsB + row * 128 + ((slot ^ (lr & 7)) << 4));
      }
    }
#pragma unroll
    for (int m = 0; m < 4; ++m)
#pragma unroll
      for (int n = 0; n < 4; ++n) {
        acc[m][n] = __builtin_amdgcn_mfma_f32_16x16x32_bf16(
            af[m][0], bfr[n][0], acc[m][n], 0, 0, 0);
        acc[m][n] = __builtin_amdgcn_mfma_f32_16x16x32_bf16(
            af[m][1], bfr[n][1], acc[m][n], 0, 0, 0);
      }
  }

  const int or0 = bm + wm * 64 + lk * 4;
  const int oc0 = bn + wn * 64 + lr;
#pragma unroll
  for (int m = 0; m < 4; ++m)
#pragma unroll
    for (int n = 0; n < 4; ++n)
#pragma unroll
      for (int r = 0; r < 4; ++r) {
        float v = acc[m][n][r];
        const size_t off = (size_t)(or0 + m * 16 + r) * N + (oc0 + n * 16);
        if (SPLITK > 1) {
          ((bf16_t*)Cout)[bz * MN + off] = (bf16_t)v;  // bf16 partial
        } else {
          if (RELU) v = fmaxf(v, 0.f);
          if (ADDF32OUT)
            ((float*)Cout)[off] = v + add[off];
          else
            ((bf16_t*)Cout)[off] = (bf16_t)v;
        }
      }
}

// reduce 6 bf16 partials -> relu -> bf16
__global__ __launch_bounds__(256) void reduce6_kernel(
    const bf16_t* __restrict__ p, bf16_t* __restrict__ out, int n8,
    size_t MN) {
  int i = blockIdx.x * 256 + threadIdx.x;
  if (i >= n8) return;
  float s[8] = {};
#pragma unroll
  for (int z = 0; z < 6; ++z) {
    bf16x8 v = *(const bf16x8*)(p + z * MN + (size_t)i * 8);
#pragma unroll
    for (int j = 0; j < 8; ++j) s[j] += (float)v[j];
  }
  bf16x8 o;
#pragma unroll
  for (int j = 0; j < 8; ++j) o[j] = (bf16_t)fmaxf(s[j], 0.f);
  *(bf16x8*)(out + (size_t)i * 8) = o;
}

// ---------------------------------------------------------------------------
__global__ __launch_bounds__(256) void cvt_bf16_kernel(
    const float* __restrict__ in, bf16_t* __restrict__ out, int n4) {
  int i = blockIdx.x * 256 + threadIdx.x;
  if (i >= n4) return;
  float4 v = ((const float4*)in)[i];
  bf16x4 o = {(bf16_t)v.x, (bf16_t)v.y, (bf16_t)v.z, (bf16_t)v.w};
  ((bf16x4*)out)[i] = o;
}

// ---------------------------------------------------------------------------
// W[K][N] fp32 -> Wt[N][K] bf16, 32x32 LDS tile transpose
// ---------------------------------------------------------------------------
__global__ __launch_bounds__(256) void transT_kernel(
    const float* __restrict__ in, bf16_t* __restrict__ out, int K, int N) {
  __shared__ float t[32][33];
  const int n0 = blockIdx.x * 32, k0 = blockIdx.y * 32;
  const int tx = threadIdx.x & 31, ty = threadIdx.x >> 5;  // 32 x 8
#pragma unroll
  for (int i = 0; i < 4; ++i)
    t[ty + i * 8][tx] = in[(size_t)(k0 + ty + i * 8) * N + n0 + tx];
  __syncthreads();
#pragma unroll
  for (int i = 0; i < 4; ++i)
    out[(size_t)(n0 + ty + i * 8) * K + k0 + tx] = (bf16_t)t[tx][ty + i * 8];
}

// ---------------------------------------------------------------------------
// Conv chain (algebraically restructured; see R2 notes)
// ---------------------------------------------------------------------------
__global__ __launch_bounds__(256) void prep_w1r_kernel(
    const float* __restrict__ w1, float* __restrict__ w1r) {
  int idx = blockIdx.x * 256 + threadIdx.x;
  if (idx >= NRCH * 90) return;
  int ci = idx / 90, r = idx % 90, k9 = r / 10, co = r % 10;
  w1r[idx] = w1[((co * NRCH + ci) * 3 + k9 / 3) * 3 + (k9 % 3)];
}

__global__ __launch_bounds__(128) void prep_w23_kernel(
    const float* __restrict__ w2, const float* __restrict__ w3,
    float* __restrict__ w23) {
  int t = threadIdx.x;
  if (t >= 90) return;
  int k9 = t / 10, c2 = t % 10;
  float acc = 0.f;
#pragma unroll
  for (int c3 = 0; c3 < 5; ++c3)
    acc += w3[c3] * w2[((c3 * 10 + c2) * 3 + k9 / 3) * 3 + (k9 % 3)];
  w23[t] = acc;
}

__global__ __launch_bounds__(256) void pidx_kernel(
    const int* __restrict__ preds, int* __restrict__ pidx) {
  int idx = blockIdx.x * 256 + threadIdx.x;
  if (idx >= BDIM * NOBJ * NOBJ) return;
  int j = idx % NOBJ;
  int i = (idx / NOBJ) % NOBJ;
  int b = idx / (NOBJ * NOBJ);
  pidx[idx] = preds[b * NOBJ + i] * NCC + preds[b * NOBJ + j];
}

__global__ __launch_bounds__(128) void femb1_kernel(
    const float* __restrict__ femb, const float* __restrict__ w1r,
    float* __restrict__ femb1) {
  __shared__ float row[NRCH];
  const int p = blockIdx.x;
  if (threadIdx.x < NRCH)
    row[threadIdx.x] = femb[(size_t)p * NRCH + threadIdx.x];
  __syncthreads();
  const int t = threadIdx.x;
  if (t >= 90) return;
  float acc = 0.f;
#pragma unroll
  for (int ci = 0; ci < NRCH; ++ci) acc += row[ci] * w1r[ci * 90 + t];
  femb1[((size_t)p * 9 + t / 10) * 12 + (t % 10)] = acc;
}

__global__ __launch_bounds__(256) void conv1g_kernel(
    const int* __restrict__ pidx, const float* __restrict__ femb1,
    float* __restrict__ x1) {
  int idx = blockIdx.x * 256 + threadIdx.x;
  if (idx >= BDIM * NOBJ * NOBJ) return;
  int j = idx % NOBJ;
  int i = (idx / NOBJ) % NOBJ;
  int b = idx / (NOBJ * NOBJ);
  f32x4 a0 = {0.f, 0.f, 0.f, 0.f}, a1 = a0, a2 = a0;
  const int* pb = pidx + b * NOBJ * NOBJ;
#pragma unroll
  for (int kh = 0; kh < 3; ++kh) {
    int ii = i + kh - 1;
    if (ii < 0 || ii >= NOBJ) continue;
#pragma unroll
    for (int kw = 0; kw < 3; ++kw) {
      int jj = j + kw - 1;
      if (jj < 0 || jj >= NOBJ) continue;
      int p = pb[ii * NOBJ + jj];
      const f32x4* f =
          (const f32x4*)(femb1 + ((size_t)p * 9 + kh * 3 + kw) * 12);
      a0 += f[0];
      a1 += f[1];
      a2 += f[2];
    }
  }
  f32x4* o = (f32x4*)(x1 + (size_t)idx * 12);
  o[0] = a0;
  o[1] = a1;
  o[2] = a2;
}

__global__ __launch_bounds__(256) void conv23_kernel(
    const float* __restrict__ x1, const float* __restrict__ w23,
    float* __restrict__ adj) {
  __shared__ float w[90];
  if (threadIdx.x < 90) w[threadIdx.x] = w23[threadIdx.x];
  __syncthreads();
  int idx = blockIdx.x * 256 + threadIdx.x;
  if (idx >= BDIM * NOBJ * NOBJ) return;
  int j = idx % NOBJ;
  int i = (idx / NOBJ) % NOBJ;
  int b = idx / (NOBJ * NOBJ);
  float acc = 0.f;
  const float* xb = x1 + (size_t)b * NOBJ * NOBJ * 12;
#pragma unroll
  for (int kh = 0; kh < 3; ++kh) {
    int ii = i + kh - 1;
    if (ii < 0 || ii >= NOBJ) continue;
#pragma unroll
    for (int kw = 0; kw < 3; ++kw) {
      int jj = j + kw - 1;
      if (jj < 0 || jj >= NOBJ) continue;
      const float* xr = xb + (ii * NOBJ + jj) * 12;
      const float* wr = w + (kh * 3 + kw) * 10;
#pragma unroll
      for (int c = 0; c < 10; ++c) acc += wr[c] * xr[c];
    }
  }
  adj[idx] = tanhf(acc);
}

// ---------------------------------------------------------------------------
// einsum via MFMA: ofl_u[b] = adj[b] (100x100) @ u1[b] (100x1024)
// Block = (h-slice of 128, batch). A = adj rows (k=m contiguous).
// B = u1 slice transposed IN LDS during staging (per-lane ds_write_b16
// scatter, slot-XOR swizzle -> conflict-free; verified: banks
// (slot^h&7)*4 + (m%8)/2 span all 32 for 64 consecutive m).
// K padded 100->128; both LDS tiles pre-zeroed so pad contributes 0 (and no
// garbage NaN*0). Fragment/epilogue mapping identical to gemm_bf16 (proven).
// ---------------------------------------------------------------------------
__global__ __launch_bounds__(256) void einsum_mfma_kernel(
    const float* __restrict__ adj,    // [32][100][100]
    const bf16_t* __restrict__ u1,    // [3200][1024]
    bf16_t* __restrict__ ofl) {       // [3200][1024]
  __shared__ __align__(16) bf16_t As[128 * 128];  // [n-row][k=m] swizzled
  __shared__ __align__(16) bf16_t Us[128 * 128];  // [h-col][k=m] swizzled
  const int b = blockIdx.y;
  const int h0 = blockIdx.x * 128;
  const int tid = threadIdx.x, lane = tid & 63, w = tid >> 6;
  const int wm = w >> 1, wn = w & 1;
  const int lr = lane & 15, lk = lane >> 4;

  // pre-zero both tiles (k/m padding + NaN safety)
  {
    f32x4 z = {0.f, 0.f, 0.f, 0.f};
#pragma unroll
    for (int i = 0; i < 8; ++i) ((f32x4*)As)[tid + i * 256] = z;
#pragma unroll
    for (int i = 0; i < 8; ++i) ((f32x4*)Us)[tid + i * 256] = z;
  }
  __syncthreads();

  // stage A: adj[b] 100x100 fp32 -> bf16, swizzled [row][k]
  const float* ab = adj + (size_t)b * 10000;
#pragma unroll
  for (int i = 0; i < 10; ++i) {
    int idx = tid + i * 256;  // 2500 f32x4 chunks (row-contiguous)
    if (idx < 2500) {
      int row = idx / 25, kc = idx % 25;  // k = kc*4..kc*4+3
      f32x4 v = ((const f32x4*)ab)[idx];
      bf16x4 o = {(bf16_t)v[0], (bf16_t)v[1], (bf16_t)v[2], (bf16_t)v[3]};
      int slot = kc >> 1;
      *(bf16x4*)((char*)As + row * 256 + ((slot ^ (row & 7)) << 4) +
                 (kc & 1) * 8) = o;
    }
  }

  // stage U^T: u1 rows m (coalesced-ish bf16x8 of 8 h-cols), scatter to
  // Us[h][k=m] swizzled
  const bf16_t* ub = u1 + (size_t)b * 100 * HDIM + h0;
#pragma unroll
  for (int i = 0; i < 7; ++i) {
    int idx = tid + i * 256;  // 16 h-chunks x 100 m
    if (idx < 1600) {
      int hc = idx / 100, m = idx % 100;
      bf16x8 v = *(const bf16x8*)(ub + (size_t)m * HDIM + hc * 8);
      int slot = m >> 3, mr = m & 7;
#pragma unroll
      for (int j = 0; j < 8; ++j) {
        int h = hc * 8 + j;
        *((bf16_t*)((char*)Us + h * 256 + ((slot ^ (h & 7)) << 4) + mr * 2)) =
            v[j];
      }
    }
  }
  __syncthreads();

  f32x4 acc[4][4];
#pragma unroll
  for (int m = 0; m < 4; ++m)
#pragma unroll
    for (int n = 0; n < 4; ++n) acc[m][n] = (f32x4){0.f, 0.f, 0.f, 0.f};

#pragma unroll
  for (int ks = 0; ks < 4; ++ks) {
    bf16x8 a[4], u[4];
#pragma unroll
    for (int m = 0; m < 4; ++m) {
      int row = wm * 64 + m * 16 + lr;
      int slot = ks * 4 + lk;
      a[m] = *(const bf16x8*)((char*)As + row * 256 + ((slot ^ (lr & 7)) << 4));
    }
#pragma unroll
    for (int n = 0; n < 4; ++n) {
      int row = wn * 64 + n * 16 + lr;
      int slot = ks * 4 + lk;
      u[n] = *(const bf16x8*)((char*)Us + row * 256 + ((slot ^ (lr & 7)) << 4));
    }
#pragma unroll
    for (int m = 0; m < 4; ++m)
#pragma unroll
      for (int n = 0; n < 4; ++n)
        acc[m][n] =
            __builtin_amdgcn_mfma_f32_16x16x32_bf16(a[m], u[n], acc[m][n], 0, 0, 0);
  }

  const int or0 = wm * 64 + lk * 4;
  const int oc0 = h0 + wn * 64 + lr;
#pragma unroll
  for (int m = 0; m < 4; ++m)
#pragma unroll
    for (int n = 0; n < 4; ++n)
#pragma unroll
      for (int r = 0; r < 4; ++r) {
        int row = or0 + m * 16 + r;
        if (row < 100)
          ofl[((size_t)b * 100 + row) * HDIM + oc0 + n * 16] =
              (bf16_t)acc[m][n][r];
      }
}

// ---------------------------------------------------------------------------
extern "C" void kernel_launch(void* const* d_in, const int* in_sizes, int n_in,
                              void* d_out, int out_size, void* d_ws,
                              size_t ws_size, hipStream_t stream) {
  const float* enc = (const float*)d_in[0];
  const float* W_comp = (const float*)d_in[1];
  const float* W_ou1 = (const float*)d_in[2];
  const float* W_ofc = (const float*)d_in[3];
  const float* W_dec = (const float*)d_in[4];
  const float* conv1w = (const float*)d_in[5];
  const float* conv2w = (const float*)d_in[6];
  const float* conv3w = (const float*)d_in[7];
  const float* femb = (const float*)d_in[8];
  const int* preds = (const int*)d_in[9];
  float* out = (float*)d_out;
  char* wsb = (char*)d_ws;

  const size_t MN = (size_t)TDIM * HDIM;  // 3,276,800

  // workspace (bytes), peak 80.5MB (proven budget >= 92.3MB from R1):
  // G1: encb[0,26.2M) WcompT[26.2,34.6M) comp[34.6,41.16M)
  //     part6[41.16M, 80.48M)  (6 x 6.55MB bf16 partials, dead after reduce6)
  // Wou1T aliases part6 start after reduce6; conv region [43.25M, 77.6M)
  // written after reduce6 too. phase C [0, 23.6M).
  bf16_t* encb   = (bf16_t*)(wsb + 0);           // 26,214,400
  bf16_t* WcompT = (bf16_t*)(wsb + 26214400);    //  8,388,608
  bf16_t* comp   = (bf16_t*)(wsb + 34603008);    //  6,553,600
  bf16_t* part6  = (bf16_t*)(wsb + 41156608);    // 39,321,600 (ends 80.48M)
  bf16_t* Wou1T  = (bf16_t*)(wsb + 41156608);    //  2,097,152 (after reduce)
  float*  w1r    = (float*)(wsb + 43253760);     //     18,360
  float*  w23    = (float*)(wsb + 43272128);     //        360
  float*  femb1  = (float*)(wsb + 43272512);     //  9,850,032
  int*    pidx   = (int*)(wsb + 53122560);       //  1,280,000
  float*  x1     = (float*)(wsb + 54402560);     // 15,360,000
  bf16_t* obj_u1 = (bf16_t*)(wsb + 69762560);    //  6,553,600
  float*  adj    = (float*)(wsb + 76316160);     //  1,280,000 (ends 77.6M)
  bf16_t* ofl_u  = (bf16_t*)(wsb + 0);           //  6,553,600
  bf16_t* WofcT  = (bf16_t*)(wsb + 6553600);     //  2,097,152
  bf16_t* u_m    = (bf16_t*)(wsb + 8650752);     //  6,553,600
  bf16_t* WdecT  = (bf16_t*)(wsb + 15204352);    //  8,388,608 (ends 23.6M)

  // --- conversions for GEMM1 ---
  cvt_bf16_kernel<<<(TDIM * DDIM / 4 + 255) / 256, 256, 0, stream>>>(
      enc, encb, TDIM * DDIM / 4);
  transT_kernel<<<dim3(HDIM / 32, DDIM / 32), 256, 0, stream>>>(
      W_comp, WcompT, DDIM, HDIM);

  // 1. comp = relu(enc @ W_comp)   M=3200 N=1024 K=4096, split-K=6 (bf16)
  gemm_bf16<false, false, 6>
      <<<dim3(HDIM / 128, TDIM / 128, 6), 256, 0, stream>>>(
          encb, WcompT, nullptr, part6, HDIM, DDIM, MN);
  reduce6_kernel<<<(int)(MN / 8 / 256), 256, 0, stream>>>(part6, comp,
                                                          (int)(MN / 8), MN);

  // 2. obj_u1 = relu(comp @ W_ou1) M=3200 N=1024 K=1024
  transT_kernel<<<dim3(HDIM / 32, HDIM / 32), 256, 0, stream>>>(
      W_ou1, Wou1T, HDIM, HDIM);
  gemm_bf16<true, false, 1>
      <<<dim3(HDIM / 128, TDIM / 128), 256, 0, stream>>>(
          comp, Wou1T, nullptr, obj_u1, HDIM, HDIM, MN);

  // 3. conv chain precomputes
  prep_w1r_kernel<<<(NRCH * 90 + 255) / 256, 256, 0, stream>>>(conv1w, w1r);
  prep_w23_kernel<<<1, 128, 0, stream>>>(conv2w, conv3w, w23);
  pidx_kernel<<<(BDIM * NOBJ * NOBJ + 255) / 256, 256, 0, stream>>>(preds,
                                                                    pidx);
  femb1_kernel<<<NCC * NCC, 128, 0, stream>>>(femb, w1r, femb1);

  // 4. conv1 via gather-sum; 5. conv2+conv3+tanh fused
  conv1g_kernel<<<(BDIM * NOBJ * NOBJ + 255) / 256, 256, 0, stream>>>(
      pidx, femb1, x1);
  conv23_kernel<<<(BDIM * NOBJ * NOBJ + 255) / 256, 256, 0, stream>>>(x1, w23,
                                                                      adj);

  // conversions for GEMM3/4
  transT_kernel<<<dim3(HDIM / 32, HDIM / 32), 256, 0, stream>>>(
      W_ofc, WofcT, HDIM, HDIM);
  transT_kernel<<<dim3(DDIM / 32, HDIM / 32), 256, 0, stream>>>(
      W_dec, WdecT, HDIM, DDIM);

  // 7. einsum via MFMA -> ofl_u (bf16)
  einsum_mfma_kernel<<<dim3(HDIM / 128, BDIM), 256, 0, stream>>>(adj, obj_u1,
                                                                 ofl_u);

  // 8. u_m = relu(ofl_u @ W_ofc)   M=3200 N=1024 K=1024
  gemm_bf16<true, false, 1>
      <<<dim3(HDIM / 128, TDIM / 128), 256, 0, stream>>>(
          ofl_u, WofcT, nullptr, u_m, HDIM, HDIM, MN);
  // 9. out = relu(u_m @ W_dec) + enc   M=3200 N=4096 K=1024  (fp32 out)
  gemm_bf16<true, true, 1>
      <<<dim3(DDIM / 128, TDIM / 128), 256, 0, stream>>>(
          u_m, WdecT, enc, out, DDIM, HDIM, MN);
}